// Round 1
// baseline (129.740 us; speedup 1.0000x reference)
//
#include <hip/hip_runtime.h>

// SimpleRelativeAttention collapses twice:
// 1. einsum 'bnqk,bnqe->bnqe' multiplies v by softmax row-sums (==1) -> attention
//    is an identity on v. rel_table/rel_index/q/k are dead.
// 2. out = x @ Wv @ Wproj + (b_v @ Wproj + b_proj); fold W_c = Wv @ Wproj
//    (1024^3 mini-GEMM) so the hot path is ONE 4096x1024x1024 GEMM.
// Timed window includes ~88us of harness poison/restore overhead (rocprof:
// fillBufferAligned 268MB @43us each); our controllable budget is the ~40us
// of kernel time.
// This round: both GEMMs get an explicit LDS double-buffer + 2-phase prefetch
// (T3-minimum template): stage tile t+1 BEFORE computing tile t, single
// raw s_barrier + vmcnt(0) per k-step (after MFMA). Rationale: grid=256 blocks
// = 1 block/CU, so there is no inter-block wave overlap to hide the
// __syncthreads() vmcnt-drain of the old serial structure — every one of the
// 16 k-iterations paid full staging latency.

#define DIMC 1024
#define MTOT 4096   // BATCH * SEQ

__device__ __forceinline__ unsigned short f2bf(float f) {
  unsigned u = __float_as_uint(f);
  u += 0x7FFFu + ((u >> 16) & 1u);   // round-to-nearest-even
  return (unsigned short)(u >> 16);
}

typedef __attribute__((ext_vector_type(8))) short short8;
typedef __attribute__((ext_vector_type(4))) float floatx4;

__device__ __forceinline__ void async_copy16(const unsigned short* g, unsigned short* l) {
  __builtin_amdgcn_global_load_lds(
      (const __attribute__((address_space(1))) unsigned int*)g,
      (__attribute__((address_space(3))) unsigned int*)l,
      16, 0, 0);
}

// fp32 -> bf16 elementwise, 4 elems/thread (contiguous)
__global__ void cast_bf16_kernel(const float* __restrict__ in,
                                 unsigned short* __restrict__ out) {
  int i = (blockIdx.x * 256 + threadIdx.x) * 4;
  float4 f = *(const float4*)(in + i);
  ushort4 o;
  o.x = f2bf(f.x); o.y = f2bf(f.y); o.z = f2bf(f.z); o.w = f2bf(f.w);
  *(ushort4*)(out + i) = o;
}

// Fused weight prep, grid (32,32) x 256 thr. Block (bx,by):
//  - WpT[n][j] = w_proj[j][n] for j in by-tile, n in bx-tile (LDS transpose)
//  - Wvb[k][j2] = w_qkv[k][2048+j2] for k in by-tile, j2 in bx-tile (cast)
//  - b_c[n] += sum_{j in by-tile} b_v[j] * w_proj[j][n] (reuses LDS tile;
//    b_c zeroed by hipMemsetAsync; b_proj added in main GEMM epilogue)
__global__ void prep_kernel(const float* __restrict__ w_proj,
                            const float* __restrict__ w_qkv,
                            const float* __restrict__ b_v,
                            unsigned short* __restrict__ WpT,
                            unsigned short* __restrict__ Wvb,
                            float* __restrict__ b_c) {
  __shared__ float tile[32][33];
  const int t = threadIdx.x;
  const int tx = t & 31, ty = t >> 5;
  const int bx = blockIdx.x, by = blockIdx.y;
#pragma unroll
  for (int r = 0; r < 4; ++r) {
    int kl = ty + r * 8;
    tile[kl][tx] = w_proj[(size_t)(by * 32 + kl) * DIMC + bx * 32 + tx];
  }
  {  // w_qkv slice cast (independent of LDS)
    const int r2 = t >> 3, c4 = (t & 7) * 4;
    float4 f = *(const float4*)(w_qkv + (size_t)(by * 32 + r2) * (3 * DIMC) +
                                2 * DIMC + bx * 32 + c4);
    ushort4 o;
    o.x = f2bf(f.x); o.y = f2bf(f.y); o.z = f2bf(f.z); o.w = f2bf(f.w);
    *(ushort4*)(Wvb + (size_t)(by * 32 + r2) * DIMC + bx * 32 + c4) = o;
  }
  __syncthreads();
#pragma unroll
  for (int r = 0; r < 4; ++r) {
    int nl = ty + r * 8;
    WpT[(size_t)(bx * 32 + nl) * DIMC + by * 32 + tx] = f2bf(tile[tx][nl]);
  }
  if (t < 32) {
    float s = 0.f;
#pragma unroll
    for (int kl = 0; kl < 32; ++kl) s += b_v[by * 32 + kl] * tile[kl][t];
    atomicAdd(&b_c[bx * 32 + t], s);
  }
}

// C[M,N] = A[M,K] @ Bt[N,K]^T (+ bias[N] + bias2[N])
// BM x BN block tile, BK=64, 256 threads = 4 waves in 2x2, wave tile
// (BM/2)x(BN/2), 16x16x32 bf16 MFMA. global_load_lds width-16 staging with
// global-side XOR swizzle of the k-chunk (chunk c holds row=c>>3,
// kc=(c&7)^(row&7)) so ds_read_b128 fragment reads are bank-conflict-free
// while staging stays coalesced (permutation within a 128B row segment).
// Double-buffered LDS + 2-phase prefetch: stage k-tile t+1 before computing
// t; ONE raw s_barrier + vmcnt(0) per k-step, placed AFTER the MFMAs so the
// prefetch stays in flight under ds_read+MFMA (grid = 1 block/CU -> no
// inter-block overlap; in-wave prefetch is the only latency hiding).
// SWZ: XCD-aware 1D-grid decode so each XCD keeps a narrow A row-range +
// all of B in its private L2 (speed heuristic only).
template <int BM, int BN, bool BF16_OUT, bool SWZ>
__global__ __launch_bounds__(256, 2) void gemm_bt_kernel(
    const unsigned short* __restrict__ A,   // [M,K] bf16
    const unsigned short* __restrict__ Bt,  // [N,K] bf16
    const float* __restrict__ bias,         // [N] or nullptr
    const float* __restrict__ bias2,        // [N] or nullptr
    void* __restrict__ Cout, int M, int N, int K, int gx) {
  constexpr int MI = BM / 32;   // m-frags per wave
  constexpr int NI = BN / 32;   // n-frags per wave
  constexpr int AG = BM / 32;   // A staging glls per thread
  constexpr int BG = BN / 32;   // B staging glls per thread
  __shared__ __align__(16) unsigned short As[2][BM * 64];
  __shared__ __align__(16) unsigned short Bs[2][BN * 64];

  const int tid = threadIdx.x;
  const int wv = tid >> 6;
  const int lane = tid & 63;

  int bx, by;
  if (SWZ) {  // 256 blocks: xcd = bid&7 gets x=all, y in [4*xcd, 4*xcd+4)
    const int bid = blockIdx.x;
    bx = (bid >> 3) & 7;
    by = (bid & 7) * 4 + (bid >> 6);
  } else {
    bx = blockIdx.x % gx;
    by = blockIdx.x / gx;
  }
  const int m0 = by * BM;
  const int n0 = bx * BN;

  floatx4 acc[MI][NI] = {};

  // staging addresses (swizzled k-chunk; row-invariant since rows step by 32)
  const int srow = tid >> 3;                 // 0..31
  const int skc = (tid & 7) ^ (srow & 7);    // swizzled k-chunk
  const unsigned short* Ag[AG];
  const unsigned short* Bg[BG];
#pragma unroll
  for (int g = 0; g < AG; ++g)
    Ag[g] = A + (size_t)(m0 + g * 32 + srow) * K + skc * 8;
#pragma unroll
  for (int g = 0; g < BG; ++g)
    Bg[g] = Bt + (size_t)(n0 + g * 32 + srow) * K + skc * 8;

  const int lr = lane & 15;
  const int qr = lane >> 4;
  const int lx = lr & 7;                     // fragment-read swizzle key
  const int wrow = (wv >> 1) * (BM / 2);
  const int wcol = (wv & 1) * (BN / 2);

  const int NT = K >> 6;                     // k-tiles (16 for K=1024)

  // prologue: stage tile 0, drain, barrier
#pragma unroll
  for (int g = 0; g < AG; ++g)
    async_copy16(Ag[g], As[0] + (g * 256 + wv * 64) * 8);
#pragma unroll
  for (int g = 0; g < BG; ++g)
    async_copy16(Bg[g], Bs[0] + (g * 256 + wv * 64) * 8);
  asm volatile("s_waitcnt vmcnt(0)" ::: "memory");
  __builtin_amdgcn_s_barrier();

  int cur = 0;
  for (int t = 0; t < NT; ++t) {
    const unsigned short* Asc = As[cur];
    const unsigned short* Bsc = Bs[cur];
    const bool pre = (t + 1 < NT);
    if (pre) {  // issue prefetch of tile t+1 into the other buffer
      const int nxt = cur ^ 1;
      const int kn = (t + 1) * 64;
#pragma unroll
      for (int g = 0; g < AG; ++g)
        async_copy16(Ag[g] + kn, As[nxt] + (g * 256 + wv * 64) * 8);
#pragma unroll
      for (int g = 0; g < BG; ++g)
        async_copy16(Bg[g] + kn, Bs[nxt] + (g * 256 + wv * 64) * 8);
    }

    short8 a[2][MI], b[2][NI];
#pragma unroll
    for (int s = 0; s < 2; ++s) {
      const int kphys = ((s * 4 + qr) ^ lx) * 8;
#pragma unroll
      for (int mi = 0; mi < MI; ++mi)
        a[s][mi] = *(const short8*)(Asc + (wrow + mi * 16 + lr) * 64 + kphys);
#pragma unroll
      for (int ni = 0; ni < NI; ++ni)
        b[s][ni] = *(const short8*)(Bsc + (wcol + ni * 16 + lr) * 64 + kphys);
    }
#pragma unroll
    for (int s = 0; s < 2; ++s)
#pragma unroll
      for (int mi = 0; mi < MI; ++mi)
#pragma unroll
        for (int ni = 0; ni < NI; ++ni)
          acc[mi][ni] = __builtin_amdgcn_mfma_f32_16x16x32_bf16(a[s][mi], b[s][ni],
                                                                acc[mi][ni], 0, 0, 0);
    if (pre) {
      // one drain+barrier per k-step: next tile resident AND every wave done
      // reading buf[cur] before it is overwritten at t+1
      asm volatile("s_waitcnt vmcnt(0)" ::: "memory");
      __builtin_amdgcn_s_barrier();
    }
    cur ^= 1;
  }

  // epilogue: C row = m0+wrow+mi*16+qr*4+r, col = n0+wcol+ni*16+lr
#pragma unroll
  for (int mi = 0; mi < MI; ++mi) {
#pragma unroll
    for (int ni = 0; ni < NI; ++ni) {
      const int col = n0 + wcol + ni * 16 + lr;
      float bv = 0.0f;
      if (bias)  bv += bias[col];
      if (bias2) bv += bias2[col];
#pragma unroll
      for (int r = 0; r < 4; ++r) {
        const int row = m0 + wrow + mi * 16 + qr * 4 + r;
        const float val = acc[mi][ni][r] + bv;
        if (BF16_OUT)
          ((unsigned short*)Cout)[(size_t)row * N + col] = f2bf(val);
        else
          ((float*)Cout)[(size_t)row * N + col] = val;
      }
    }
  }
}

extern "C" void kernel_launch(void* const* d_in, const int* in_sizes, int n_in,
                              void* d_out, int out_size, void* d_ws, size_t ws_size,
                              hipStream_t stream) {
  const float* x      = (const float*)d_in[0];  // [4,1024,1024]
  const float* w_qkv  = (const float*)d_in[1];  // [1024,3072]
  const float* b_qkv  = (const float*)d_in[2];  // [3072]
  const float* w_proj = (const float*)d_in[3];  // [1024,1024]
  const float* b_proj = (const float*)d_in[4];  // [1024]
  // d_in[5]=rel_table, d_in[6]=rel_index unused (softmax rows sum to 1).
  float* out = (float*)d_out;

  char* ws = (char*)d_ws;
  unsigned short* xb  = (unsigned short*)(ws);                       // 8 MB [4096,1024]
  unsigned short* WpT = (unsigned short*)(ws + (size_t)(8u << 20));  // 2 MB WpT[n][j]=w_proj[j][n]
  unsigned short* Wvb = (unsigned short*)(ws + (size_t)(10u << 20)); // 2 MB Wvb[k][j]=w_qkv[k][2048+j]
  unsigned short* WcT = (unsigned short*)(ws + (size_t)(12u << 20)); // 2 MB WcT[n][k]=W_c[k][n]
  float*          b_c = (float*)(ws + (size_t)(14u << 20));          // 4 KB

  // 1. b_c zero-init (prep_kernel atomicAdds into it)
  hipMemsetAsync(b_c, 0, DIMC * sizeof(float), stream);
  // 2. x -> bf16
  cast_bf16_kernel<<<(MTOT * DIMC) / (256 * 4), 256, 0, stream>>>(x, xb);
  // 3. fused: WpT transpose-cast, Wvb slice-cast, b_c partial matvec
  prep_kernel<<<dim3(32, 32), 256, 0, stream>>>(w_proj, w_qkv, b_qkv + 2 * DIMC,
                                                WpT, Wvb, b_c);
  // 4. WcT[n][k] = sum_j WpT[n][j] * Wvb[k][j]  (64x64 tile, 256 blocks, dbuf)
  gemm_bt_kernel<64, 64, true, false><<<256, 256, 0, stream>>>(
      WpT, Wvb, nullptr, nullptr, WcT, DIMC, DIMC, DIMC, DIMC / 64);
  // 5. out = xb @ WcT^T + (b_c + b_proj)  (128x128 tile, 256 blocks, XCD swizzle, dbuf)
  gemm_bt_kernel<128, 128, false, true><<<256, 256, 0, stream>>>(
      xb, WcT, b_c, b_proj, out, MTOT, DIMC, DIMC, DIMC / 128);
}